// Round 4
// baseline (469.595 us; speedup 1.0000x reference)
//
#include <hip/hip_runtime.h>

#define IN_FEATS 128
#define OUT_FEATS 64
#define TM 64              // rows per linear block
#define BW_LOG 6           // bucket width = 64 nodes
#define BWIDTH 64
#define MAX_NB 1024        // max coarse buckets supported by LDS arrays
#define SE_PER_BLK 4096    // edges staged per block (256 thr x 16)

__device__ inline void fma4(float4& a, float s, const float4& v) {
    a.x += s * v.x; a.y += s * v.y; a.z += s * v.z; a.w += s * v.w;
}

// ---------------- Linear: h = feat @ W^T + b ----------------
__global__ __launch_bounds__(256) void linear_gemm(
    const float* __restrict__ feat, const float* __restrict__ W,
    const float* __restrict__ b, float* __restrict__ h, int n_nodes)
{
    __shared__ float fs[TM * IN_FEATS];
    __shared__ float wt[IN_FEATS * OUT_FEATS];
    const int tid  = threadIdx.x;
    const int row0 = blockIdx.x * TM;

    {
        const int c  = tid & 63;
        const int kb = (tid >> 6) * 32;
        const float4* wrow = (const float4*)(W + (size_t)c * IN_FEATS + kb);
#pragma unroll
        for (int i = 0; i < 8; ++i) {
            float4 t = wrow[i];
            int k = kb + i * 4;
            wt[(k + 0) * OUT_FEATS + c] = t.x;
            wt[(k + 1) * OUT_FEATS + c] = t.y;
            wt[(k + 2) * OUT_FEATS + c] = t.z;
            wt[(k + 3) * OUT_FEATS + c] = t.w;
        }
    }
    {
#pragma unroll
        for (int i = 0; i < 8; ++i) {
            int flat = i * 256 + tid;
            int r  = flat >> 5;
            int kc = flat & 31;
            int gr = row0 + r;
            float4 t = (gr < n_nodes)
                ? ((const float4*)(feat + (size_t)gr * IN_FEATS))[kc]
                : make_float4(0.f, 0.f, 0.f, 0.f);
            *((float4*)&fs[r * IN_FEATS + kc * 4]) = t;
        }
    }
    __syncthreads();

    const int tx = tid & 15;
    const int ty = tid >> 4;

    float4 acc[4];
#pragma unroll
    for (int i = 0; i < 4; ++i) acc[i] = make_float4(0.f, 0.f, 0.f, 0.f);

    for (int k = 0; k < IN_FEATS; k += 4) {
        float4 fv[4], wv[4];
#pragma unroll
        for (int i = 0; i < 4; ++i)
            fv[i] = *((const float4*)&fs[(ty * 4 + i) * IN_FEATS + k]);
#pragma unroll
        for (int j = 0; j < 4; ++j)
            wv[j] = *((const float4*)&wt[(k + j) * OUT_FEATS + tx * 4]);
#pragma unroll
        for (int i = 0; i < 4; ++i) {
            fma4(acc[i], fv[i].x, wv[0]);
            fma4(acc[i], fv[i].y, wv[1]);
            fma4(acc[i], fv[i].z, wv[2]);
            fma4(acc[i], fv[i].w, wv[3]);
        }
    }

    float4 b4 = ((const float4*)b)[tx];
#pragma unroll
    for (int i = 0; i < 4; ++i) {
        int r = row0 + ty * 4 + i;
        if (r < n_nodes) {
            float4 o = acc[i];
            o.x += b4.x; o.y += b4.y; o.z += b4.z; o.w += b4.w;
            ((float4*)(h + (size_t)r * OUT_FEATS))[tx] = o;
        }
    }
}

// ---------------- Coarse histogram over dst>>6 ----------------
__global__ __launch_bounds__(256) void coarse_hist(
    const int* __restrict__ edst, int* __restrict__ ghist, int n_edges, int nb)
{
    __shared__ int hist[MAX_NB];
    const int tid = threadIdx.x;
    for (int i = tid; i < nb; i += 256) hist[i] = 0;
    __syncthreads();

    const int n4 = n_edges >> 2;
    const int4* ed4 = (const int4*)edst;
    for (int i = blockIdx.x * 256 + tid; i < n4; i += gridDim.x * 256) {
        int4 d = ed4[i];
        atomicAdd(&hist[d.x >> BW_LOG], 1);
        atomicAdd(&hist[d.y >> BW_LOG], 1);
        atomicAdd(&hist[d.z >> BW_LOG], 1);
        atomicAdd(&hist[d.w >> BW_LOG], 1);
    }
    if (blockIdx.x == 0 && tid < (n_edges & 3))
        atomicAdd(&hist[edst[n4 * 4 + tid] >> BW_LOG], 1);
    __syncthreads();
    for (int i = tid; i < nb; i += 256)
        if (hist[i]) atomicAdd(&ghist[i], hist[i]);
}

// ---------------- Single-block exclusive scan of nb (<=1024) counters --------
__global__ __launch_bounds__(256) void coarse_scan(
    const int* __restrict__ ghist, int* __restrict__ goff,
    int* __restrict__ gcur, int nb)
{
    __shared__ int wsum[4];
    __shared__ int wpre[4];
    const int tid  = threadIdx.x;
    const int lane = tid & 63;
    const int wv   = tid >> 6;
    int i0 = tid * 4;
    int v[4];
    int s = 0;
#pragma unroll
    for (int j = 0; j < 4; ++j) v[j] = (i0 + j < nb) ? ghist[i0 + j] : 0;
#pragma unroll
    for (int j = 0; j < 4; ++j) { int t = v[j]; v[j] = s; s += t; }
    int inc = s;
    for (int off = 1; off < 64; off <<= 1) {
        int t = __shfl_up(inc, off, 64);
        if (lane >= off) inc += t;
    }
    int wexcl = inc - s;
    if (lane == 63) wsum[wv] = inc;
    __syncthreads();
    if (tid == 0) {
        int a = 0;
        for (int k = 0; k < 4; ++k) { wpre[k] = a; a += wsum[k]; }
    }
    __syncthreads();
    int tbase = wpre[wv] + wexcl;
#pragma unroll
    for (int j = 0; j < 4; ++j) {
        int idx = i0 + j;
        if (idx < nb) { int e = tbase + v[j]; goff[idx] = e; gcur[idx] = e; }
    }
    if (tid == 0) goff[nb] = wpre[3] + wsum[3];
}

// ---------------- Stage: bin edges by coarse bucket ----------------
// Record: int2{ (dst&63)<<16 | src , bits(weight) }
__global__ __launch_bounds__(256) void stage_kernel(
    const int* __restrict__ esrc, const int* __restrict__ edst,
    const float* __restrict__ ew, int* __restrict__ gcur,
    int2* __restrict__ gstage, int n_edges, int nb)
{
    __shared__ int cnt[MAX_NB];
    __shared__ int base[MAX_NB];
    const int tid = threadIdx.x;
    const int e0  = blockIdx.x * SE_PER_BLK;

    for (int i = tid; i < nb; i += 256) cnt[i] = 0;
    __syncthreads();

    int key[16]; float w[16]; int bk[16]; int rk[16];
#pragma unroll
    for (int i = 0; i < 16; ++i) {
        int e = e0 + i * 256 + tid;
        if (e < n_edges) {
            int d = edst[e];
            int b = d >> BW_LOG;
            bk[i]  = b;
            key[i] = ((d & (BWIDTH - 1)) << 16) | esrc[e];
            w[i]   = ew[e];
            rk[i]  = atomicAdd(&cnt[b], 1);
        } else bk[i] = -1;
    }
    __syncthreads();
    for (int i = tid; i < nb; i += 256) {
        int c = cnt[i];
        base[i] = c ? atomicAdd(&gcur[i], c) : 0;
    }
    __syncthreads();
#pragma unroll
    for (int i = 0; i < 16; ++i) {
        if (bk[i] >= 0)
            gstage[base[bk[i]] + rk[i]] = make_int2(key[i], __float_as_int(w[i]));
    }
}

// ---------------- Gather: one block per bucket, LDS accumulate ----------------
__global__ __launch_bounds__(256) void gather_bin(
    const float* __restrict__ h, const int* __restrict__ goff,
    const int2* __restrict__ gstage, float* __restrict__ out, int n_nodes)
{
    __shared__ float acc[BWIDTH * OUT_FEATS];   // 16 KB
    const int tid  = threadIdx.x;
    const int lane = tid & 63;
    const int wv   = tid >> 6;
    const int b    = blockIdx.x;

    for (int i = tid; i < BWIDTH * OUT_FEATS / 4; i += 256)
        ((float4*)acc)[i] = make_float4(0.f, 0.f, 0.f, 0.f);
    __syncthreads();

    const int s0 = goff[b], s1 = goff[b + 1];
    int idx = s0 + wv;
    // 8-deep unroll: independent record loads, then independent h-row loads.
    for (; idx + 28 < s1; idx += 32) {
        int2 r[8]; float hv[8];
#pragma unroll
        for (int u = 0; u < 8; ++u) r[u] = gstage[idx + 4 * u];
#pragma unroll
        for (int u = 0; u < 8; ++u)
            hv[u] = h[(size_t)(r[u].x & 0xFFFF) * OUT_FEATS + lane];
#pragma unroll
        for (int u = 0; u < 8; ++u)
            atomicAdd(&acc[((r[u].x >> 16) << 6) + lane],
                      hv[u] * __int_as_float(r[u].y));
    }
    for (; idx < s1; idx += 4) {
        int2 r = gstage[idx];
        float hv = h[(size_t)(r.x & 0xFFFF) * OUT_FEATS + lane];
        atomicAdd(&acc[((r.x >> 16) << 6) + lane], hv * __int_as_float(r.y));
    }
    __syncthreads();

    const int node0 = b * BWIDTH;
    for (int i = tid; i < BWIDTH * OUT_FEATS / 4; i += 256) {
        int node = node0 + (i >> 4);    // 16 float4 per node
        if (node < n_nodes)
            ((float4*)out)[(size_t)node0 * 16 + i] = ((const float4*)acc)[i];
    }
}

// ---------------- Fallback atomic scatter ----------------
__global__ __launch_bounds__(256) void scatter_kernel(
    const float* __restrict__ h, const int* __restrict__ esrc,
    const int* __restrict__ edst, const float* __restrict__ ew,
    float* __restrict__ out, int n_edges)
{
    const int lane = threadIdx.x & 63;
    const int wave = threadIdx.x >> 6;
    const int stride = gridDim.x * 4;
    for (int e = blockIdx.x * 4 + wave; e < n_edges; e += stride) {
        const int s = esrc[e];
        const int d = edst[e];
        const float w = ew[e];
        atomicAdd(out + (size_t)d * OUT_FEATS + lane,
                  h[(size_t)s * OUT_FEATS + lane] * w);
    }
}

extern "C" void kernel_launch(void* const* d_in, const int* in_sizes, int n_in,
                              void* d_out, int out_size, void* d_ws, size_t ws_size,
                              hipStream_t stream) {
    const float* feat = (const float*)d_in[0];
    const int*   esrc = (const int*)d_in[1];
    const int*   edst = (const int*)d_in[2];
    const float* ew   = (const float*)d_in[3];
    const float* W    = (const float*)d_in[4];
    const float* b    = (const float*)d_in[5];
    float* out = (float*)d_out;

    const int n_nodes = in_sizes[0] / IN_FEATS;  // 50000
    const int n_edges = in_sizes[1];             // 800000
    const int nb = (n_nodes + BWIDTH - 1) >> BW_LOG;  // 782

    // ws: h | ghist(nb) | goff(nb+1) | gcur(nb) | gstage(E int2)
    char* wsb = (char*)d_ws;
    float* h = (float*)wsb;
    size_t off_ghist = (size_t)n_nodes * OUT_FEATS * sizeof(float);
    size_t sz_ghist  = (((size_t)nb * sizeof(int)) + 15) & ~(size_t)15;
    size_t off_goff  = off_ghist + sz_ghist;
    size_t sz_goff   = (((size_t)(nb + 1) * sizeof(int)) + 15) & ~(size_t)15;
    size_t off_gcur  = off_goff + sz_goff;
    size_t sz_gcur   = (((size_t)nb * sizeof(int)) + 15) & ~(size_t)15;
    size_t off_stage = off_gcur + sz_gcur;
    size_t needed    = off_stage + (size_t)n_edges * sizeof(int2);

    linear_gemm<<<(n_nodes + TM - 1) / TM, 256, 0, stream>>>(feat, W, b, h, n_nodes);

    if (ws_size >= needed && nb <= MAX_NB && n_nodes < 65536) {
        int*  ghist  = (int*)(wsb + off_ghist);
        int*  goff   = (int*)(wsb + off_goff);
        int*  gcur   = (int*)(wsb + off_gcur);
        int2* gstage = (int2*)(wsb + off_stage);
        hipMemsetAsync(ghist, 0, (size_t)nb * sizeof(int), stream);
        coarse_hist<<<128, 256, 0, stream>>>(edst, ghist, n_edges, nb);
        coarse_scan<<<1, 256, 0, stream>>>(ghist, goff, gcur, nb);
        stage_kernel<<<(n_edges + SE_PER_BLK - 1) / SE_PER_BLK, 256, 0, stream>>>(
            esrc, edst, ew, gcur, gstage, n_edges, nb);
        gather_bin<<<nb, 256, 0, stream>>>(h, goff, gstage, out, n_nodes);
    } else {
        hipMemsetAsync(d_out, 0, (size_t)out_size * sizeof(float), stream);
        scatter_kernel<<<8192, 256, 0, stream>>>(h, esrc, edst, ew, out, n_edges);
    }
}

// Round 5
// 174.765 us; speedup vs baseline: 2.6870x; 2.6870x over previous
//
#include <hip/hip_runtime.h>

#define IN_FEATS 128
#define OUT_FEATS 64
#define TM 64              // rows per linear block
#define BW_LOG 6           // bucket width = 64 nodes
#define BWIDTH 64
#define MAX_NB 1024        // max coarse buckets supported by LDS arrays
#define SE_PER_BLK 4096    // edges staged per block (256 thr x 16)
#define MAX_BUCKET 3072    // max records per bucket for bin_sort LDS (24 KB)

__device__ inline void fma4(float4& a, float s, const float4& v) {
    a.x += s * v.x; a.y += s * v.y; a.z += s * v.z; a.w += s * v.w;
}

// ---------------- Linear: h = feat @ W^T + b ----------------
__global__ __launch_bounds__(256) void linear_gemm(
    const float* __restrict__ feat, const float* __restrict__ W,
    const float* __restrict__ b, float* __restrict__ h, int n_nodes)
{
    __shared__ float fs[TM * IN_FEATS];
    __shared__ float wt[IN_FEATS * OUT_FEATS];
    const int tid  = threadIdx.x;
    const int row0 = blockIdx.x * TM;

    {
        const int c  = tid & 63;
        const int kb = (tid >> 6) * 32;
        const float4* wrow = (const float4*)(W + (size_t)c * IN_FEATS + kb);
#pragma unroll
        for (int i = 0; i < 8; ++i) {
            float4 t = wrow[i];
            int k = kb + i * 4;
            wt[(k + 0) * OUT_FEATS + c] = t.x;
            wt[(k + 1) * OUT_FEATS + c] = t.y;
            wt[(k + 2) * OUT_FEATS + c] = t.z;
            wt[(k + 3) * OUT_FEATS + c] = t.w;
        }
    }
    {
#pragma unroll
        for (int i = 0; i < 8; ++i) {
            int flat = i * 256 + tid;
            int r  = flat >> 5;
            int kc = flat & 31;
            int gr = row0 + r;
            float4 t = (gr < n_nodes)
                ? ((const float4*)(feat + (size_t)gr * IN_FEATS))[kc]
                : make_float4(0.f, 0.f, 0.f, 0.f);
            *((float4*)&fs[r * IN_FEATS + kc * 4]) = t;
        }
    }
    __syncthreads();

    const int tx = tid & 15;
    const int ty = tid >> 4;

    float4 acc[4];
#pragma unroll
    for (int i = 0; i < 4; ++i) acc[i] = make_float4(0.f, 0.f, 0.f, 0.f);

    for (int k = 0; k < IN_FEATS; k += 4) {
        float4 fv[4], wv[4];
#pragma unroll
        for (int i = 0; i < 4; ++i)
            fv[i] = *((const float4*)&fs[(ty * 4 + i) * IN_FEATS + k]);
#pragma unroll
        for (int j = 0; j < 4; ++j)
            wv[j] = *((const float4*)&wt[(k + j) * OUT_FEATS + tx * 4]);
#pragma unroll
        for (int i = 0; i < 4; ++i) {
            fma4(acc[i], fv[i].x, wv[0]);
            fma4(acc[i], fv[i].y, wv[1]);
            fma4(acc[i], fv[i].z, wv[2]);
            fma4(acc[i], fv[i].w, wv[3]);
        }
    }

    float4 b4 = ((const float4*)b)[tx];
#pragma unroll
    for (int i = 0; i < 4; ++i) {
        int r = row0 + ty * 4 + i;
        if (r < n_nodes) {
            float4 o = acc[i];
            o.x += b4.x; o.y += b4.y; o.z += b4.z; o.w += b4.w;
            ((float4*)(h + (size_t)r * OUT_FEATS))[tx] = o;
        }
    }
}

// ---------------- Coarse histogram over dst>>6 ----------------
__global__ __launch_bounds__(256) void coarse_hist(
    const int* __restrict__ edst, int* __restrict__ ghist, int n_edges, int nb)
{
    __shared__ int hist[MAX_NB];
    const int tid = threadIdx.x;
    for (int i = tid; i < nb; i += 256) hist[i] = 0;
    __syncthreads();

    const int n4 = n_edges >> 2;
    const int4* ed4 = (const int4*)edst;
    for (int i = blockIdx.x * 256 + tid; i < n4; i += gridDim.x * 256) {
        int4 d = ed4[i];
        atomicAdd(&hist[d.x >> BW_LOG], 1);
        atomicAdd(&hist[d.y >> BW_LOG], 1);
        atomicAdd(&hist[d.z >> BW_LOG], 1);
        atomicAdd(&hist[d.w >> BW_LOG], 1);
    }
    if (blockIdx.x == 0 && tid < (n_edges & 3))
        atomicAdd(&hist[edst[n4 * 4 + tid] >> BW_LOG], 1);
    __syncthreads();
    for (int i = tid; i < nb; i += 256)
        if (hist[i]) atomicAdd(&ghist[i], hist[i]);
}

// ---------------- Single-block exclusive scan of nb (<=1024) counters --------
__global__ __launch_bounds__(256) void coarse_scan(
    const int* __restrict__ ghist, int* __restrict__ goff,
    int* __restrict__ gcur, int nb)
{
    __shared__ int wsum[4];
    __shared__ int wpre[4];
    const int tid  = threadIdx.x;
    const int lane = tid & 63;
    const int wv   = tid >> 6;
    int i0 = tid * 4;
    int v[4];
    int s = 0;
#pragma unroll
    for (int j = 0; j < 4; ++j) v[j] = (i0 + j < nb) ? ghist[i0 + j] : 0;
#pragma unroll
    for (int j = 0; j < 4; ++j) { int t = v[j]; v[j] = s; s += t; }
    int inc = s;
    for (int off = 1; off < 64; off <<= 1) {
        int t = __shfl_up(inc, off, 64);
        if (lane >= off) inc += t;
    }
    int wexcl = inc - s;
    if (lane == 63) wsum[wv] = inc;
    __syncthreads();
    if (tid == 0) {
        int a = 0;
        for (int k = 0; k < 4; ++k) { wpre[k] = a; a += wsum[k]; }
    }
    __syncthreads();
    int tbase = wpre[wv] + wexcl;
#pragma unroll
    for (int j = 0; j < 4; ++j) {
        int idx = i0 + j;
        if (idx < nb) { int e = tbase + v[j]; goff[idx] = e; gcur[idx] = e; }
    }
    if (tid == 0) goff[nb] = wpre[3] + wsum[3];
}

// ---------------- Stage: bin edges by coarse bucket ----------------
// Record: int2{ (dst&63)<<16 | src , bits(weight) }
__global__ __launch_bounds__(256) void stage_kernel(
    const int* __restrict__ esrc, const int* __restrict__ edst,
    const float* __restrict__ ew, int* __restrict__ gcur,
    int2* __restrict__ gstage, int n_edges, int nb)
{
    __shared__ int cnt[MAX_NB];
    __shared__ int base[MAX_NB];
    const int tid = threadIdx.x;
    const int e0  = blockIdx.x * SE_PER_BLK;

    for (int i = tid; i < nb; i += 256) cnt[i] = 0;
    __syncthreads();

    int key[16]; float w[16]; int bk[16]; int rk[16];
#pragma unroll
    for (int i = 0; i < 16; ++i) {
        int e = e0 + i * 256 + tid;
        if (e < n_edges) {
            int d = edst[e];
            int b = d >> BW_LOG;
            bk[i]  = b;
            key[i] = ((d & (BWIDTH - 1)) << 16) | esrc[e];
            w[i]   = ew[e];
            rk[i]  = atomicAdd(&cnt[b], 1);
        } else bk[i] = -1;
    }
    __syncthreads();
    for (int i = tid; i < nb; i += 256) {
        int c = cnt[i];
        base[i] = c ? atomicAdd(&gcur[i], c) : 0;
    }
    __syncthreads();
#pragma unroll
    for (int i = 0; i < 16; ++i) {
        if (bk[i] >= 0)
            gstage[base[bk[i]] + rk[i]] = make_int2(key[i], __float_as_int(w[i]));
    }
}

// ---------------- Bin-sort: bucket -> exact CSR (in place) ----------------
// One block per bucket. Loads bucket records to LDS, histograms the 64
// node slots, wave-scans, writes records back sorted-by-node and emits
// per-node offsets. All global writes are to this block's own region.
__global__ __launch_bounds__(256) void bin_sort(
    int2* __restrict__ gstage, const int* __restrict__ goff,
    int* __restrict__ goff_fine, int n_nodes, int nb)
{
    __shared__ int2 recs[MAX_BUCKET];
    __shared__ int cnt[BWIDTH];
    __shared__ int cur[BWIDTH];
    const int tid = threadIdx.x;
    const int b   = blockIdx.x;
    const int s0  = goff[b], s1 = goff[b + 1];
    const int m   = s1 - s0;   // bucket size (stat bound << MAX_BUCKET)

    if (tid < BWIDTH) cnt[tid] = 0;
    __syncthreads();

    for (int i = tid; i < m; i += 256) {
        int2 r = gstage[s0 + i];
        recs[i] = r;
        atomicAdd(&cnt[(r.x >> 16) & 63], 1);
    }
    __syncthreads();

    if (tid < 64) {
        int v = cnt[tid];
        int inc = v;
        for (int o = 1; o < 64; o <<= 1) {
            int t = __shfl_up(inc, o, 64);
            if (tid >= o) inc += t;
        }
        int excl = inc - v;
        cur[tid] = excl;
        int node = b * BWIDTH + tid;
        if (node < n_nodes) goff_fine[node] = s0 + excl;
        if (b == nb - 1 && tid == 63) goff_fine[n_nodes] = s1;
    }
    __syncthreads();

    for (int i = tid; i < m; i += 256) {
        int2 r = recs[i];
        int pos = atomicAdd(&cur[(r.x >> 16) & 63], 1);
        gstage[s0 + pos] = r;
    }
}

// ---------------- Gather: one wave per dst node over exact CSR ----------------
__global__ __launch_bounds__(256) void gather_kernel(
    const float* __restrict__ h, const int* __restrict__ offsets,
    const int2* __restrict__ perm2, float* __restrict__ out, int n_nodes)
{
    int wave = (blockIdx.x * blockDim.x + threadIdx.x) >> 6;
    int lane = threadIdx.x & 63;
    if (wave >= n_nodes) return;
    int s0 = offsets[wave], s1 = offsets[wave + 1];
    float acc = 0.f;
    int idx = s0;
    for (; idx + 3 < s1; idx += 4) {
        int2 m0 = perm2[idx];
        int2 m1 = perm2[idx + 1];
        int2 m2 = perm2[idx + 2];
        int2 m3 = perm2[idx + 3];
        float h0 = h[(size_t)(m0.x & 0xFFFF) * OUT_FEATS + lane];
        float h1 = h[(size_t)(m1.x & 0xFFFF) * OUT_FEATS + lane];
        float h2 = h[(size_t)(m2.x & 0xFFFF) * OUT_FEATS + lane];
        float h3 = h[(size_t)(m3.x & 0xFFFF) * OUT_FEATS + lane];
        acc += h0 * __int_as_float(m0.y);
        acc += h1 * __int_as_float(m1.y);
        acc += h2 * __int_as_float(m2.y);
        acc += h3 * __int_as_float(m3.y);
    }
    for (; idx < s1; ++idx) {
        int2 m = perm2[idx];
        acc += h[(size_t)(m.x & 0xFFFF) * OUT_FEATS + lane] * __int_as_float(m.y);
    }
    out[(size_t)wave * OUT_FEATS + lane] = acc;
}

// ---------------- Fallback atomic scatter ----------------
__global__ __launch_bounds__(256) void scatter_kernel(
    const float* __restrict__ h, const int* __restrict__ esrc,
    const int* __restrict__ edst, const float* __restrict__ ew,
    float* __restrict__ out, int n_edges)
{
    const int lane = threadIdx.x & 63;
    const int wave = threadIdx.x >> 6;
    const int stride = gridDim.x * 4;
    for (int e = blockIdx.x * 4 + wave; e < n_edges; e += stride) {
        const int s = esrc[e];
        const int d = edst[e];
        const float w = ew[e];
        atomicAdd(out + (size_t)d * OUT_FEATS + lane,
                  h[(size_t)s * OUT_FEATS + lane] * w);
    }
}

extern "C" void kernel_launch(void* const* d_in, const int* in_sizes, int n_in,
                              void* d_out, int out_size, void* d_ws, size_t ws_size,
                              hipStream_t stream) {
    const float* feat = (const float*)d_in[0];
    const int*   esrc = (const int*)d_in[1];
    const int*   edst = (const int*)d_in[2];
    const float* ew   = (const float*)d_in[3];
    const float* W    = (const float*)d_in[4];
    const float* b    = (const float*)d_in[5];
    float* out = (float*)d_out;

    const int n_nodes = in_sizes[0] / IN_FEATS;  // 50000
    const int n_edges = in_sizes[1];             // 800000
    const int nb = (n_nodes + BWIDTH - 1) >> BW_LOG;  // 782

    // ws: h | ghist(nb) | goff(nb+1) | gcur(nb) | goff_fine(n+1) | gstage(E int2)
    char* wsb = (char*)d_ws;
    float* h = (float*)wsb;
    size_t off_ghist = (size_t)n_nodes * OUT_FEATS * sizeof(float);
    size_t sz_ghist  = (((size_t)nb * sizeof(int)) + 15) & ~(size_t)15;
    size_t off_goff  = off_ghist + sz_ghist;
    size_t sz_goff   = (((size_t)(nb + 1) * sizeof(int)) + 15) & ~(size_t)15;
    size_t off_gcur  = off_goff + sz_goff;
    size_t sz_gcur   = (((size_t)nb * sizeof(int)) + 15) & ~(size_t)15;
    size_t off_fine  = off_gcur + sz_gcur;
    size_t sz_fine   = (((size_t)(n_nodes + 1) * sizeof(int)) + 15) & ~(size_t)15;
    size_t off_stage = off_fine + sz_fine;
    size_t needed    = off_stage + (size_t)n_edges * sizeof(int2);

    linear_gemm<<<(n_nodes + TM - 1) / TM, 256, 0, stream>>>(feat, W, b, h, n_nodes);

    // Mean bucket load must stay well under MAX_BUCKET for the in-LDS sort.
    bool binnable = (nb <= MAX_NB) && (n_nodes < 65536) &&
                    ((size_t)n_edges / (size_t)nb * 2 + 256 <= MAX_BUCKET);

    if (ws_size >= needed && binnable) {
        int*  ghist  = (int*)(wsb + off_ghist);
        int*  goff   = (int*)(wsb + off_goff);
        int*  gcur   = (int*)(wsb + off_gcur);
        int*  gfine  = (int*)(wsb + off_fine);
        int2* gstage = (int2*)(wsb + off_stage);
        hipMemsetAsync(ghist, 0, (size_t)nb * sizeof(int), stream);
        coarse_hist<<<128, 256, 0, stream>>>(edst, ghist, n_edges, nb);
        coarse_scan<<<1, 256, 0, stream>>>(ghist, goff, gcur, nb);
        stage_kernel<<<(n_edges + SE_PER_BLK - 1) / SE_PER_BLK, 256, 0, stream>>>(
            esrc, edst, ew, gcur, gstage, n_edges, nb);
        bin_sort<<<nb, 256, 0, stream>>>(gstage, goff, gfine, n_nodes, nb);
        gather_kernel<<<((size_t)n_nodes * 64 + 255) / 256, 256, 0, stream>>>(
            h, gfine, gstage, out, n_nodes);
    } else {
        hipMemsetAsync(d_out, 0, (size_t)out_size * sizeof(float), stream);
        scatter_kernel<<<8192, 256, 0, stream>>>(h, esrc, edst, ew, out, n_edges);
    }
}

// Round 6
// 167.056 us; speedup vs baseline: 2.8110x; 1.0461x over previous
//
#include <hip/hip_runtime.h>

#define IN_FEATS 128
#define OUT_FEATS 64
#define TM 64              // rows per linear block
#define FS_LD 132          // padded LDS leading dim (breaks 4-way bank alias)
#define BW_LOG 6           // bucket width = 64 nodes
#define BWIDTH 64
#define MAX_NB 1024        // max coarse buckets supported by LDS arrays
#define SE_PER_BLK 4096    // edges staged per block (256 thr x 16)
#define MAX_BUCKET 3072    // max records per bucket for bin_sort LDS (24 KB)

__device__ inline void fma4(float4& a, float s, const float4& v) {
    a.x += s * v.x; a.y += s * v.y; a.z += s * v.z; a.w += s * v.w;
}
__device__ inline unsigned short f2bf(float f) {   // RTNE fp32 -> bf16
    unsigned u = __float_as_uint(f);
    u += 0x7FFFu + ((u >> 16) & 1u);
    return (unsigned short)(u >> 16);
}
__device__ inline float bf2f(unsigned short v) {
    return __uint_as_float(((unsigned)v) << 16);
}

// ---------------- Linear: h = bf16(feat @ W^T + b) ----------------
__global__ __launch_bounds__(256) void linear_gemm(
    const float* __restrict__ feat, const float* __restrict__ W,
    const float* __restrict__ b, unsigned short* __restrict__ h, int n_nodes)
{
    __shared__ float fs[TM * FS_LD];              // padded rows
    __shared__ float wt[IN_FEATS * OUT_FEATS];
    const int tid  = threadIdx.x;
    const int row0 = blockIdx.x * TM;

    {
        const int c  = tid & 63;
        const int kb = (tid >> 6) * 32;
        const float4* wrow = (const float4*)(W + (size_t)c * IN_FEATS + kb);
#pragma unroll
        for (int i = 0; i < 8; ++i) {
            float4 t = wrow[i];
            int k = kb + i * 4;
            wt[(k + 0) * OUT_FEATS + c] = t.x;
            wt[(k + 1) * OUT_FEATS + c] = t.y;
            wt[(k + 2) * OUT_FEATS + c] = t.z;
            wt[(k + 3) * OUT_FEATS + c] = t.w;
        }
    }
    {
#pragma unroll
        for (int i = 0; i < 8; ++i) {
            int flat = i * 256 + tid;
            int r  = flat >> 5;
            int kc = flat & 31;
            int gr = row0 + r;
            float4 t = (gr < n_nodes)
                ? ((const float4*)(feat + (size_t)gr * IN_FEATS))[kc]
                : make_float4(0.f, 0.f, 0.f, 0.f);
            *((float4*)&fs[r * FS_LD + kc * 4]) = t;
        }
    }
    __syncthreads();

    const int tx = tid & 15;
    const int ty = tid >> 4;

    float4 acc[4];
#pragma unroll
    for (int i = 0; i < 4; ++i) acc[i] = make_float4(0.f, 0.f, 0.f, 0.f);

    for (int k = 0; k < IN_FEATS; k += 4) {
        float4 fv[4], wv[4];
#pragma unroll
        for (int i = 0; i < 4; ++i)
            fv[i] = *((const float4*)&fs[(ty * 4 + i) * FS_LD + k]);
#pragma unroll
        for (int j = 0; j < 4; ++j)
            wv[j] = *((const float4*)&wt[(k + j) * OUT_FEATS + tx * 4]);
#pragma unroll
        for (int i = 0; i < 4; ++i) {
            fma4(acc[i], fv[i].x, wv[0]);
            fma4(acc[i], fv[i].y, wv[1]);
            fma4(acc[i], fv[i].z, wv[2]);
            fma4(acc[i], fv[i].w, wv[3]);
        }
    }

    float4 b4 = ((const float4*)b)[tx];
#pragma unroll
    for (int i = 0; i < 4; ++i) {
        int r = row0 + ty * 4 + i;
        if (r < n_nodes) {
            float4 o = acc[i];
            o.x += b4.x; o.y += b4.y; o.z += b4.z; o.w += b4.w;
            ushort4 s4;
            s4.x = f2bf(o.x); s4.y = f2bf(o.y);
            s4.z = f2bf(o.z); s4.w = f2bf(o.w);
            *((ushort4*)&h[(size_t)r * OUT_FEATS + tx * 4]) = s4;
        }
    }
}

// ---------------- Coarse histogram over dst>>6 ----------------
__global__ __launch_bounds__(256) void coarse_hist(
    const int* __restrict__ edst, int* __restrict__ ghist, int n_edges, int nb)
{
    __shared__ int hist[MAX_NB];
    const int tid = threadIdx.x;
    for (int i = tid; i < nb; i += 256) hist[i] = 0;
    __syncthreads();

    const int n4 = n_edges >> 2;
    const int4* ed4 = (const int4*)edst;
    for (int i = blockIdx.x * 256 + tid; i < n4; i += gridDim.x * 256) {
        int4 d = ed4[i];
        atomicAdd(&hist[d.x >> BW_LOG], 1);
        atomicAdd(&hist[d.y >> BW_LOG], 1);
        atomicAdd(&hist[d.z >> BW_LOG], 1);
        atomicAdd(&hist[d.w >> BW_LOG], 1);
    }
    if (blockIdx.x == 0 && tid < (n_edges & 3))
        atomicAdd(&hist[edst[n4 * 4 + tid] >> BW_LOG], 1);
    __syncthreads();
    for (int i = tid; i < nb; i += 256)
        if (hist[i]) atomicAdd(&ghist[i], hist[i]);
}

// ---------------- Single-block exclusive scan of nb (<=1024) counters --------
__global__ __launch_bounds__(256) void coarse_scan(
    const int* __restrict__ ghist, int* __restrict__ goff,
    int* __restrict__ gcur, int nb)
{
    __shared__ int wsum[4];
    __shared__ int wpre[4];
    const int tid  = threadIdx.x;
    const int lane = tid & 63;
    const int wv   = tid >> 6;
    int i0 = tid * 4;
    int v[4];
    int s = 0;
#pragma unroll
    for (int j = 0; j < 4; ++j) v[j] = (i0 + j < nb) ? ghist[i0 + j] : 0;
#pragma unroll
    for (int j = 0; j < 4; ++j) { int t = v[j]; v[j] = s; s += t; }
    int inc = s;
    for (int off = 1; off < 64; off <<= 1) {
        int t = __shfl_up(inc, off, 64);
        if (lane >= off) inc += t;
    }
    int wexcl = inc - s;
    if (lane == 63) wsum[wv] = inc;
    __syncthreads();
    if (tid == 0) {
        int a = 0;
        for (int k = 0; k < 4; ++k) { wpre[k] = a; a += wsum[k]; }
    }
    __syncthreads();
    int tbase = wpre[wv] + wexcl;
#pragma unroll
    for (int j = 0; j < 4; ++j) {
        int idx = i0 + j;
        if (idx < nb) { int e = tbase + v[j]; goff[idx] = e; gcur[idx] = e; }
    }
    if (tid == 0) goff[nb] = wpre[3] + wsum[3];
}

// ---------------- Stage: bin edges by coarse bucket ----------------
// Record: int2{ (dst&63)<<16 | src , bits(weight) }  (src < 65536 guarded)
__global__ __launch_bounds__(256) void stage_kernel(
    const int* __restrict__ esrc, const int* __restrict__ edst,
    const float* __restrict__ ew, int* __restrict__ gcur,
    int2* __restrict__ gstage, int n_edges, int nb)
{
    __shared__ int cnt[MAX_NB];
    __shared__ int base[MAX_NB];
    const int tid = threadIdx.x;
    const int e0  = blockIdx.x * SE_PER_BLK;

    for (int i = tid; i < nb; i += 256) cnt[i] = 0;
    __syncthreads();

    int key[16]; float w[16]; int bk[16]; int rk[16];
#pragma unroll
    for (int i = 0; i < 16; ++i) {
        int e = e0 + i * 256 + tid;
        if (e < n_edges) {
            int d = edst[e];
            int b = d >> BW_LOG;
            bk[i]  = b;
            key[i] = ((d & (BWIDTH - 1)) << 16) | esrc[e];
            w[i]   = ew[e];
            rk[i]  = atomicAdd(&cnt[b], 1);
        } else bk[i] = -1;
    }
    __syncthreads();
    for (int i = tid; i < nb; i += 256) {
        int c = cnt[i];
        base[i] = c ? atomicAdd(&gcur[i], c) : 0;
    }
    __syncthreads();
#pragma unroll
    for (int i = 0; i < 16; ++i) {
        if (bk[i] >= 0)
            gstage[base[bk[i]] + rk[i]] = make_int2(key[i], __float_as_int(w[i]));
    }
}

// ---------------- Bin-sort: bucket -> exact CSR (in place) ----------------
__global__ __launch_bounds__(256) void bin_sort(
    int2* __restrict__ gstage, const int* __restrict__ goff,
    int* __restrict__ goff_fine, int n_nodes, int nb)
{
    __shared__ int2 recs[MAX_BUCKET];
    __shared__ int cnt[BWIDTH];
    __shared__ int cur[BWIDTH];
    const int tid = threadIdx.x;
    const int b   = blockIdx.x;
    const int s0  = goff[b], s1 = goff[b + 1];
    const int m   = s1 - s0;

    if (tid < BWIDTH) cnt[tid] = 0;
    __syncthreads();

    for (int i = tid; i < m; i += 256) {
        int2 r = gstage[s0 + i];
        recs[i] = r;
        atomicAdd(&cnt[(r.x >> 16) & 63], 1);
    }
    __syncthreads();

    if (tid < 64) {
        int v = cnt[tid];
        int inc = v;
        for (int o = 1; o < 64; o <<= 1) {
            int t = __shfl_up(inc, o, 64);
            if (tid >= o) inc += t;
        }
        int excl = inc - v;
        cur[tid] = excl;
        int node = b * BWIDTH + tid;
        if (node < n_nodes) goff_fine[node] = s0 + excl;
        if (b == nb - 1 && tid == 63) goff_fine[n_nodes] = s1;
    }
    __syncthreads();

    for (int i = tid; i < m; i += 256) {
        int2 r = recs[i];
        int pos = atomicAdd(&cur[(r.x >> 16) & 63], 1);
        gstage[s0 + pos] = r;
    }
}

// ---------------- Gather: one wave per dst node over exact CSR ----------------
__global__ __launch_bounds__(256) void gather_kernel(
    const unsigned short* __restrict__ h, const int* __restrict__ offsets,
    const int2* __restrict__ perm2, float* __restrict__ out, int n_nodes)
{
    int wave = (blockIdx.x * blockDim.x + threadIdx.x) >> 6;
    int lane = threadIdx.x & 63;
    if (wave >= n_nodes) return;
    int s0 = offsets[wave], s1 = offsets[wave + 1];
    float acc = 0.f;
    int idx = s0;
    for (; idx + 7 < s1; idx += 8) {
        int2 r[8]; float hv[8];
#pragma unroll
        for (int u = 0; u < 8; ++u) r[u] = perm2[idx + u];
#pragma unroll
        for (int u = 0; u < 8; ++u)
            hv[u] = bf2f(h[(size_t)(r[u].x & 0xFFFF) * OUT_FEATS + lane]);
#pragma unroll
        for (int u = 0; u < 8; ++u)
            acc += hv[u] * __int_as_float(r[u].y);
    }
    for (; idx < s1; ++idx) {
        int2 m = perm2[idx];
        acc += bf2f(h[(size_t)(m.x & 0xFFFF) * OUT_FEATS + lane])
               * __int_as_float(m.y);
    }
    out[(size_t)wave * OUT_FEATS + lane] = acc;
}

// ---------------- Fallback atomic scatter ----------------
__global__ __launch_bounds__(256) void scatter_kernel(
    const unsigned short* __restrict__ h, const int* __restrict__ esrc,
    const int* __restrict__ edst, const float* __restrict__ ew,
    float* __restrict__ out, int n_edges)
{
    const int lane = threadIdx.x & 63;
    const int wave = threadIdx.x >> 6;
    const int stride = gridDim.x * 4;
    for (int e = blockIdx.x * 4 + wave; e < n_edges; e += stride) {
        const int s = esrc[e];
        const int d = edst[e];
        const float w = ew[e];
        atomicAdd(out + (size_t)d * OUT_FEATS + lane,
                  bf2f(h[(size_t)s * OUT_FEATS + lane]) * w);
    }
}

extern "C" void kernel_launch(void* const* d_in, const int* in_sizes, int n_in,
                              void* d_out, int out_size, void* d_ws, size_t ws_size,
                              hipStream_t stream) {
    const float* feat = (const float*)d_in[0];
    const int*   esrc = (const int*)d_in[1];
    const int*   edst = (const int*)d_in[2];
    const float* ew   = (const float*)d_in[3];
    const float* W    = (const float*)d_in[4];
    const float* b    = (const float*)d_in[5];
    float* out = (float*)d_out;

    const int n_nodes = in_sizes[0] / IN_FEATS;  // 50000
    const int n_edges = in_sizes[1];             // 800000
    const int nb = (n_nodes + BWIDTH - 1) >> BW_LOG;  // 782

    // ws: h(bf16) | ghist(nb) | goff(nb+1) | gcur(nb) | goff_fine(n+1) | gstage(E int2)
    char* wsb = (char*)d_ws;
    unsigned short* h = (unsigned short*)wsb;
    size_t off_ghist = (((size_t)n_nodes * OUT_FEATS * sizeof(unsigned short)) + 15) & ~(size_t)15;
    size_t sz_ghist  = (((size_t)nb * sizeof(int)) + 15) & ~(size_t)15;
    size_t off_goff  = off_ghist + sz_ghist;
    size_t sz_goff   = (((size_t)(nb + 1) * sizeof(int)) + 15) & ~(size_t)15;
    size_t off_gcur  = off_goff + sz_goff;
    size_t sz_gcur   = (((size_t)nb * sizeof(int)) + 15) & ~(size_t)15;
    size_t off_fine  = off_gcur + sz_gcur;
    size_t sz_fine   = (((size_t)(n_nodes + 1) * sizeof(int)) + 15) & ~(size_t)15;
    size_t off_stage = off_fine + sz_fine;
    size_t needed    = off_stage + (size_t)n_edges * sizeof(int2);

    linear_gemm<<<(n_nodes + TM - 1) / TM, 256, 0, stream>>>(feat, W, b, h, n_nodes);

    bool binnable = (nb <= MAX_NB) && (n_nodes < 65536) &&
                    ((size_t)n_edges / (size_t)nb * 2 + 256 <= MAX_BUCKET);

    if (ws_size >= needed && binnable) {
        int*  ghist  = (int*)(wsb + off_ghist);
        int*  goff   = (int*)(wsb + off_goff);
        int*  gcur   = (int*)(wsb + off_gcur);
        int*  gfine  = (int*)(wsb + off_fine);
        int2* gstage = (int2*)(wsb + off_stage);
        hipMemsetAsync(ghist, 0, (size_t)nb * sizeof(int), stream);
        coarse_hist<<<128, 256, 0, stream>>>(edst, ghist, n_edges, nb);
        coarse_scan<<<1, 256, 0, stream>>>(ghist, goff, gcur, nb);
        stage_kernel<<<(n_edges + SE_PER_BLK - 1) / SE_PER_BLK, 256, 0, stream>>>(
            esrc, edst, ew, gcur, gstage, n_edges, nb);
        bin_sort<<<nb, 256, 0, stream>>>(gstage, goff, gfine, n_nodes, nb);
        gather_kernel<<<((size_t)n_nodes * 64 + 255) / 256, 256, 0, stream>>>(
            h, gfine, gstage, out, n_nodes);
    } else {
        hipMemsetAsync(d_out, 0, (size_t)out_size * sizeof(float), stream);
        scatter_kernel<<<8192, 256, 0, stream>>>(h, esrc, edst, ew, out, n_edges);
    }
}